// Round 1
// baseline (765.525 us; speedup 1.0000x reference)
//
#include <hip/hip_runtime.h>

// GCN 2-layer: out = A_hat( relu( A_hat( [x|mean]@W1 ) + b1 ) @ W2 ) + b2
// A_hat = D^-1/2 A D^-1/2 (no self loops), E=1.6M random edges, N=100K, F=64.
// Key identity: [x|mean]@W1 = x@W1[:64] + c, c = mean@W1[64:] (constant row).

// ---------- kernel 1: column sums of x (for mean) ----------
__global__ void colsum_kernel(const float* __restrict__ x, float* __restrict__ sums,
                              long long total) {
    int tid = threadIdx.x;
    long long g = (long long)blockIdx.x * blockDim.x + tid;
    long long stride = (long long)gridDim.x * blockDim.x;  // multiple of 64 -> column fixed
    float acc = 0.f;
    for (; g < total; g += stride) acc += x[g];
    __shared__ float s[256];
    s[tid] = acc;
    __syncthreads();
    if (tid < 64) {
        float v = s[tid] + s[tid + 64] + s[tid + 128] + s[tid + 192];
        atomicAdd(&sums[tid], v);  // column tid (since stride % 64 == 0)
    }
}

// ---------- kernel 2: in-degree via atomics (into dis buffer) ----------
__global__ void deg_kernel(const int* __restrict__ dst, float* __restrict__ dis, int e) {
    int i = blockIdx.x * blockDim.x + threadIdx.x;
    if (i < e) atomicAdd(&dis[dst[i]], 1.0f);
}

// ---------- kernel 3: dis = deg>0 ? rsqrt(deg) : 0 ; and c = mean @ W1[64:] ----------
__global__ void finalize_kernel(float* __restrict__ dis, const float* __restrict__ sums,
                                const float* __restrict__ W1, float* __restrict__ c, int n) {
    int i = blockIdx.x * blockDim.x + threadIdx.x;
    if (i < n) {
        float d = dis[i];
        dis[i] = d > 0.f ? rsqrtf(d) : 0.f;
    }
    if (blockIdx.x == 0 && threadIdx.x < 64) {
        int j = threadIdx.x;
        float inv_n = 1.0f / (float)n;
        float acc = 0.f;
        for (int k = 0; k < 64; ++k) acc += (sums[k] * inv_n) * W1[(64 + k) * 64 + j];
        c[j] = acc;
    }
}

// ---------- kernel 4: h1 = x @ W1[:64] + c  (64 rows per block, fp32 vector) ----------
__global__ void gemm1_kernel(const float* __restrict__ x, const float* __restrict__ W1,
                             const float* __restrict__ c, float* __restrict__ h1, int n) {
    __shared__ float Ws[64][64];   // W[k][j]: lanes read consecutive j -> conflict-free
    __shared__ float Xs[64][65];   // +1 pad (broadcast reads anyway, pad is free)
    int tid = threadIdx.x;
    int row0 = blockIdx.x * 64;
    for (int i = tid; i < 4096; i += 256) Ws[i >> 6][i & 63] = W1[i];
    for (int i = tid; i < 4096; i += 256) {
        int r = i >> 6, k = i & 63;
        int gr = row0 + r;
        Xs[r][k] = (gr < n) ? x[(long long)gr * 64 + k] : 0.f;
    }
    __syncthreads();
    int col = tid & 63;
    int rbase = (tid >> 6) * 16;
    float cj = c[col];
    for (int r = rbase; r < rbase + 16; ++r) {
        float acc = cj;
#pragma unroll
        for (int k = 0; k < 64; ++k) acc += Xs[r][k] * Ws[k][col];
        int gr = row0 + r;
        if (gr < n) h1[(long long)gr * 64 + col] = acc;
    }
}

// ---------- kernel 5: layer-1 edge scatter, one wave per edge ----------
__global__ void scatter1_kernel(const int* __restrict__ src, const int* __restrict__ dst,
                                const float* __restrict__ dis, const float* __restrict__ h1,
                                float* __restrict__ agg1, int e) {
    int lane = threadIdx.x & 63;
    long long eid = (long long)blockIdx.x * 4 + (threadIdx.x >> 6);
    if (eid >= e) return;
    int s = src[eid], d = dst[eid];
    float norm = dis[s] * dis[d];
    float v = h1[(long long)s * 64 + lane] * norm;
    atomicAdd(&agg1[(long long)d * 64 + lane], v);
}

// ---------- kernel 6: h2 = relu(agg1 + b1) @ W2, one wave per node ----------
__global__ void layer2_node_kernel(const float* __restrict__ agg1, const float* __restrict__ b1,
                                   const float* __restrict__ W2, float* __restrict__ h2, int n) {
    int lane = threadIdx.x & 63;
    int node = blockIdx.x * 4 + (threadIdx.x >> 6);
    if (node >= n) return;
    float t = agg1[(long long)node * 64 + lane] + b1[lane];
    t = t > 0.f ? t : 0.f;
    float v0 = t * W2[lane * 2 + 0];
    float v1 = t * W2[lane * 2 + 1];
#pragma unroll
    for (int off = 32; off > 0; off >>= 1) {
        v0 += __shfl_down(v0, off, 64);
        v1 += __shfl_down(v1, off, 64);
    }
    if (lane == 0) {
        h2[(long long)node * 2 + 0] = v0;
        h2[(long long)node * 2 + 1] = v1;
    }
}

// ---------- kernel 7: out = b2 broadcast (bias pre-init; scatter2 accumulates on top) ----------
__global__ void init_out_kernel(float* __restrict__ out, const float* __restrict__ b2, int n2) {
    int i = blockIdx.x * blockDim.x + threadIdx.x;
    if (i < n2) out[i] = b2[i & 1];
}

// ---------- kernel 8: layer-2 edge scatter (2 feats), one thread per edge ----------
__global__ void scatter2_kernel(const int* __restrict__ src, const int* __restrict__ dst,
                                const float* __restrict__ dis, const float* __restrict__ h2,
                                float* __restrict__ out, int e) {
    int i = blockIdx.x * blockDim.x + threadIdx.x;
    if (i >= e) return;
    int s = src[i], d = dst[i];
    float norm = dis[s] * dis[d];
    atomicAdd(&out[d * 2 + 0], h2[s * 2 + 0] * norm);
    atomicAdd(&out[d * 2 + 1], h2[s * 2 + 1] * norm);
}

extern "C" void kernel_launch(void* const* d_in, const int* in_sizes, int n_in,
                              void* d_out, int out_size, void* d_ws, size_t ws_size,
                              hipStream_t stream) {
    const float* x  = (const float*)d_in[0];
    const int*   ei = (const int*)d_in[1];   // harness delivers integer inputs as int32
    const float* W1 = (const float*)d_in[2];
    const float* b1 = (const float*)d_in[3];
    const float* W2 = (const float*)d_in[4];
    const float* b2 = (const float*)d_in[5];
    float* out = (float*)d_out;

    const int n = in_sizes[0] / 64;   // 100000
    const int e = in_sizes[1] / 2;    // 1600000
    const int* srcI = ei;
    const int* dstI = ei + e;

    // workspace layout (floats)
    float* ws   = (float*)d_ws;
    float* dis  = ws;                         // [n]   (deg, then dis in-place)
    float* sums = dis  + n;                   // [64]
    float* cvec = sums + 64;                  // [64]
    float* h1   = cvec + 64;                  // [n*64]
    float* agg1 = h1   + (size_t)n * 64;      // [n*64]
    float* h2   = agg1 + (size_t)n * 64;      // [n*2]

    // zero-init accumulators (ws is poisoned to 0xAA before every call)
    hipMemsetAsync(dis,  0, (size_t)n * sizeof(float), stream);
    hipMemsetAsync(sums, 0, 64 * sizeof(float), stream);
    hipMemsetAsync(agg1, 0, (size_t)n * 64 * sizeof(float), stream);

    colsum_kernel<<<1024, 256, 0, stream>>>(x, sums, (long long)n * 64);
    deg_kernel<<<(e + 255) / 256, 256, 0, stream>>>(dstI, dis, e);
    finalize_kernel<<<(n + 255) / 256, 256, 0, stream>>>(dis, sums, W1, cvec, n);
    gemm1_kernel<<<(n + 63) / 64, 256, 0, stream>>>(x, W1, cvec, h1, n);
    scatter1_kernel<<<(e + 3) / 4, 256, 0, stream>>>(srcI, dstI, dis, h1, agg1, e);
    layer2_node_kernel<<<(n + 3) / 4, 256, 0, stream>>>(agg1, b1, W2, h2, n);
    init_out_kernel<<<(2 * n + 255) / 256, 256, 0, stream>>>(out, b2, 2 * n);
    scatter2_kernel<<<(e + 255) / 256, 256, 0, stream>>>(srcI, dstI, dis, h2, out, e);
}

// Round 2
// 498.278 us; speedup vs baseline: 1.5363x; 1.5363x over previous
//
#include <hip/hip_runtime.h>

// GCN 2-layer, CSR-by-dst gather formulation (no feature-space atomics).
// out = A_hat( relu( A_hat( [x|mean]@W1 ) + b1 ) @ W2 ) + b2
// A_hat = D^-1/2 A D^-1/2. Identity: [x|mean]@W1 = x@W1[:64] + c, c = mean@W1[64:].
// Pre-scaling: h1s[s] = dis[s]*(xW1+c)[s]; layer1 out[d] = dis[d]*sum(h1s[src]) + b1.
//              h2s[s] = dis[s]*(relu(...)@W2)[s]; out[d] = dis[d]*sum(h2s[src]) + b2.

// ---------- column sums of x (for mean) ----------
__global__ void colsum_kernel(const float* __restrict__ x, float* __restrict__ sums,
                              long long total) {
    int tid = threadIdx.x;
    long long g = (long long)blockIdx.x * blockDim.x + tid;
    long long stride = (long long)gridDim.x * blockDim.x;  // multiple of 64 -> column fixed
    float acc = 0.f;
    for (; g < total; g += stride) acc += x[g];
    __shared__ float s[256];
    s[tid] = acc;
    __syncthreads();
    if (tid < 64) {
        float v = s[tid] + s[tid + 64] + s[tid + 128] + s[tid + 192];
        atomicAdd(&sums[tid], v);  // column tid (stride % 64 == 0)
    }
}

// ---------- in-degree histogram (int) ----------
__global__ void hist_kernel(const int* __restrict__ dst, int* __restrict__ deg, int e) {
    int i = blockIdx.x * blockDim.x + threadIdx.x;
    if (i < e) atomicAdd(&deg[dst[i]], 1);
}

// ---------- scan pass 1: per-256-block exclusive scan + block sums ----------
__global__ void scan1_kernel(const int* __restrict__ deg, int* __restrict__ rowstart,
                             int* __restrict__ blocksum, int n) {
    __shared__ int s[256];
    int tid = threadIdx.x;
    int i = blockIdx.x * 256 + tid;
    int v = (i < n) ? deg[i] : 0;
    s[tid] = v;
    __syncthreads();
    for (int off = 1; off < 256; off <<= 1) {
        int t = (tid >= off) ? s[tid - off] : 0;
        __syncthreads();
        s[tid] += t;
        __syncthreads();
    }
    if (i < n) rowstart[i] = s[tid] - v;  // exclusive within block
    if (tid == 255) blocksum[blockIdx.x] = s[255];
}

// ---------- scan pass 2: single-block exclusive scan of block sums ----------
__global__ void scan2_kernel(int* __restrict__ blocksum, int* __restrict__ blockoff, int nb) {
    __shared__ int s[512];
    int tid = threadIdx.x;
    int v = (tid < nb) ? blocksum[tid] : 0;
    s[tid] = v;
    __syncthreads();
    for (int off = 1; off < 512; off <<= 1) {
        int t = (tid >= off) ? s[tid - off] : 0;
        __syncthreads();
        s[tid] += t;
        __syncthreads();
    }
    if (tid < nb) blockoff[tid] = s[tid] - v;  // exclusive
}

// ---------- scan pass 3: add block offsets; init cursors ----------
__global__ void scan3_kernel(int* __restrict__ rowstart, const int* __restrict__ blockoff,
                             int* __restrict__ cursor, int n) {
    int i = blockIdx.x * blockDim.x + threadIdx.x;
    if (i < n) {
        int r = rowstart[i] + blockoff[i >> 8];
        rowstart[i] = r;
        cursor[i] = r;
    }
}

// ---------- dis = rsqrt(deg) ; c = mean @ W1[64:] ----------
__global__ void finalize_kernel(const int* __restrict__ deg, float* __restrict__ dis,
                                const float* __restrict__ sums, const float* __restrict__ W1,
                                float* __restrict__ c, int n) {
    int i = blockIdx.x * blockDim.x + threadIdx.x;
    if (i < n) {
        int d = deg[i];
        dis[i] = d > 0 ? rsqrtf((float)d) : 0.f;
    }
    if (blockIdx.x == 0 && threadIdx.x < 64) {
        int j = threadIdx.x;
        float inv_n = 1.0f / (float)n;
        float acc = 0.f;
        for (int k = 0; k < 64; ++k) acc += (sums[k] * inv_n) * W1[(64 + k) * 64 + j];
        c[j] = acc;
    }
}

// ---------- CSR fill: eidx[slot(dst)] = src ----------
__global__ void fill_kernel(const int* __restrict__ src, const int* __restrict__ dst,
                            int* __restrict__ cursor, int* __restrict__ eidx, int e) {
    int i = blockIdx.x * blockDim.x + threadIdx.x;
    if (i >= e) return;
    int d = dst[i];
    int pos = atomicAdd(&cursor[d], 1);
    eidx[pos] = src[i];
}

// ---------- h1s = dis[row] * (x @ W1[:64] + c) ----------
__global__ void gemm1_kernel(const float* __restrict__ x, const float* __restrict__ W1,
                             const float* __restrict__ c, const float* __restrict__ dis,
                             float* __restrict__ h1s, int n) {
    __shared__ float Ws[64][64];
    __shared__ float Xs[64][65];
    int tid = threadIdx.x;
    int row0 = blockIdx.x * 64;
    for (int i = tid; i < 4096; i += 256) Ws[i >> 6][i & 63] = W1[i];
    for (int i = tid; i < 4096; i += 256) {
        int r = i >> 6, k = i & 63;
        int gr = row0 + r;
        Xs[r][k] = (gr < n) ? x[(long long)gr * 64 + k] : 0.f;
    }
    __syncthreads();
    int col = tid & 63;
    int rbase = (tid >> 6) * 16;
    float cj = c[col];
    for (int r = rbase; r < rbase + 16; ++r) {
        int gr = row0 + r;
        if (gr >= n) break;
        float acc = cj;
#pragma unroll
        for (int k = 0; k < 64; ++k) acc += Xs[r][k] * Ws[k][col];
        h1s[(long long)gr * 64 + col] = dis[gr] * acc;
    }
}

// ---------- layer-1 gather + bias + relu + @W2 + src-prescale, one wave per node ----------
__global__ void gather1_kernel(const int* __restrict__ rowstart, const int* __restrict__ deg,
                               const int* __restrict__ eidx, const float* __restrict__ dis,
                               const float* __restrict__ h1s, const float* __restrict__ b1,
                               const float* __restrict__ W2, float* __restrict__ h2s, int n) {
    int lane = threadIdx.x & 63;
    int node = blockIdx.x * 4 + (threadIdx.x >> 6);
    if (node >= n) return;
    int rs = rowstart[node];
    int dn = deg[node];
    float acc = 0.f;
    int j = 0;
    for (; j + 2 <= dn; j += 2) {  // 2-way ILP on the row gathers
        int s0 = eidx[rs + j];
        int s1 = eidx[rs + j + 1];
        float a = h1s[(long long)s0 * 64 + lane];
        float b = h1s[(long long)s1 * 64 + lane];
        acc += a + b;
    }
    if (j < dn) acc += h1s[(long long)eidx[rs + j] * 64 + lane];
    float di = dis[node];
    float t = di * acc + b1[lane];
    t = fmaxf(t, 0.f);
    float v0 = t * W2[lane * 2 + 0];
    float v1 = t * W2[lane * 2 + 1];
#pragma unroll
    for (int off = 32; off > 0; off >>= 1) {
        v0 += __shfl_down(v0, off, 64);
        v1 += __shfl_down(v1, off, 64);
    }
    if (lane == 0) {
        h2s[(long long)node * 2 + 0] = di * v0;  // pre-scale for layer 2 (node as src)
        h2s[(long long)node * 2 + 1] = di * v1;
    }
}

// ---------- layer-2 gather, one thread per node ----------
__global__ void gather2_kernel(const int* __restrict__ rowstart, const int* __restrict__ deg,
                               const int* __restrict__ eidx, const float* __restrict__ dis,
                               const float* __restrict__ h2s, const float* __restrict__ b2,
                               float* __restrict__ out, int n) {
    int i = blockIdx.x * blockDim.x + threadIdx.x;
    if (i >= n) return;
    int rs = rowstart[i];
    int dn = deg[i];
    float a0 = 0.f, a1 = 0.f, b0 = 0.f, b1acc = 0.f;
    int j = 0;
    for (; j + 2 <= dn; j += 2) {
        int s0 = eidx[rs + j];
        int s1 = eidx[rs + j + 1];
        a0 += h2s[(long long)s0 * 2 + 0];
        a1 += h2s[(long long)s0 * 2 + 1];
        b0 += h2s[(long long)s1 * 2 + 0];
        b1acc += h2s[(long long)s1 * 2 + 1];
    }
    if (j < dn) {
        int s0 = eidx[rs + j];
        a0 += h2s[(long long)s0 * 2 + 0];
        a1 += h2s[(long long)s0 * 2 + 1];
    }
    float di = dis[i];
    out[(long long)i * 2 + 0] = di * (a0 + b0) + b2[0];
    out[(long long)i * 2 + 1] = di * (a1 + b1acc) + b2[1];
}

extern "C" void kernel_launch(void* const* d_in, const int* in_sizes, int n_in,
                              void* d_out, int out_size, void* d_ws, size_t ws_size,
                              hipStream_t stream) {
    const float* x  = (const float*)d_in[0];
    const int*   ei = (const int*)d_in[1];
    const float* W1 = (const float*)d_in[2];
    const float* b1 = (const float*)d_in[3];
    const float* W2 = (const float*)d_in[4];
    const float* b2 = (const float*)d_in[5];
    float* out = (float*)d_out;

    const int n = in_sizes[0] / 64;   // 100000
    const int e = in_sizes[1] / 2;    // 1600000
    const int* srcI = ei;
    const int* dstI = ei + e;
    const int nb = (n + 255) / 256;   // 391 scan blocks

    // workspace layout
    char* p = (char*)d_ws;
    int* deg      = (int*)p;               p += sizeof(int) * n;
    int* rowstart = (int*)p;               p += sizeof(int) * n;
    int* cursor   = (int*)p;               p += sizeof(int) * n;
    int* blocksum = (int*)p;               p += sizeof(int) * 512;
    int* blockoff = (int*)p;               p += sizeof(int) * 512;
    int* eidx     = (int*)p;               p += sizeof(int) * e;
    float* dis    = (float*)p;             p += sizeof(float) * n;
    float* sums   = (float*)p;             p += sizeof(float) * 64;
    float* cvec   = (float*)p;             p += sizeof(float) * 64;
    float* h1s    = (float*)p;             p += sizeof(float) * (size_t)n * 64;
    float* h2s    = (float*)p;             p += sizeof(float) * (size_t)n * 2;

    hipMemsetAsync(deg,  0, sizeof(int) * n, stream);
    hipMemsetAsync(sums, 0, sizeof(float) * 64, stream);

    colsum_kernel<<<1024, 256, 0, stream>>>(x, sums, (long long)n * 64);
    hist_kernel<<<(e + 255) / 256, 256, 0, stream>>>(dstI, deg, e);
    scan1_kernel<<<nb, 256, 0, stream>>>(deg, rowstart, blocksum, n);
    scan2_kernel<<<1, 512, 0, stream>>>(blocksum, blockoff, nb);
    scan3_kernel<<<nb, 256, 0, stream>>>(rowstart, blockoff, cursor, n);
    finalize_kernel<<<(n + 255) / 256, 256, 0, stream>>>(deg, dis, sums, W1, cvec, n);
    fill_kernel<<<(e + 255) / 256, 256, 0, stream>>>(srcI, dstI, cursor, eidx, e);
    gemm1_kernel<<<(n + 63) / 64, 256, 0, stream>>>(x, W1, cvec, dis, h1s, n);
    gather1_kernel<<<(n + 3) / 4, 256, 0, stream>>>(rowstart, deg, eidx, dis, h1s, b1, W2, h2s, n);
    gather2_kernel<<<(n + 255) / 256, 256, 0, stream>>>(rowstart, deg, eidx, dis, h2s, b2, out, n);
}

// Round 3
// 287.196 us; speedup vs baseline: 2.6655x; 1.7350x over previous
//
#include <hip/hip_runtime.h>

// GCN 2-layer, CSR-by-dst gather formulation.
// CSR build = 2-pass LDS-staged bucket sort (no write-amplified scatters).
// out = A_hat( relu( A_hat( [x|mean]@W1 ) + b1 ) @ W2 ) + b2
// Identity: [x|mean]@W1 = x@W1[:64] + c, c = mean@W1[64:].
// Pre-scaling: h1s[s] = dis[s]*(xW1+c)[s];  h2s[s] = dis[s]*(relu(.)@W2)[s].

#define BKT        64      // dst-range buckets
#define BKT_SHIFT  11      // 2048 nodes per bucket
#define NPB        2048
#define BKT_CAP    36864   // >> max bucket count (~32.7K +/- 0.2K)
#define CHUNK      2048    // edges per bucketA block
#define EPT        8       // edges per thread in bucketA

// ---------- column sums of x (for mean) ----------
__global__ void colsum_kernel(const float* __restrict__ x, float* __restrict__ sums,
                              long long total) {
    int tid = threadIdx.x;
    long long g = (long long)blockIdx.x * blockDim.x + tid;
    long long stride = (long long)gridDim.x * blockDim.x;  // multiple of 64 -> column fixed
    float acc = 0.f;
    for (; g < total; g += stride) acc += x[g];
    __shared__ float s[256];
    s[tid] = acc;
    __syncthreads();
    if (tid < 64) {
        float v = s[tid] + s[tid + 64] + s[tid + 128] + s[tid + 192];
        atomicAdd(&sums[tid], v);
    }
}

// ---------- pass A: LDS multi-split of edges into dst-range buckets ----------
__global__ void bucketA_kernel(const int* __restrict__ src, const int* __restrict__ dst,
                               int e, int2* __restrict__ pairs, int* __restrict__ cursor) {
    __shared__ int cnt[BKT], sb[BKT], gpos[BKT];
    __shared__ int2 stage[CHUNK];
    __shared__ unsigned char bb[CHUNK];
    int tid = threadIdx.x;
    int chunkStart = blockIdx.x * CHUNK;
    int v = e - chunkStart;
    if (v > CHUNK) v = CHUNK;
    if (tid < BKT) cnt[tid] = 0;
    __syncthreads();
    int myb[EPT], myoff[EPT], mys[EPT], myd[EPT];
#pragma unroll
    for (int t = 0; t < EPT; ++t) {
        int i = chunkStart + t * 256 + tid;
        myb[t] = -1;
        if (i < e) {
            mys[t] = src[i];
            myd[t] = dst[i];
            myb[t] = myd[t] >> BKT_SHIFT;
            myoff[t] = atomicAdd(&cnt[myb[t]], 1);
        }
    }
    __syncthreads();
    if (tid < BKT) sb[tid] = cnt[tid];
    __syncthreads();
    for (int off = 1; off < BKT; off <<= 1) {
        int t = (tid < BKT && tid >= off) ? sb[tid - off] : 0;
        __syncthreads();
        if (tid < BKT) sb[tid] += t;
        __syncthreads();
    }
    if (tid < BKT) {
        int excl = tid ? sb[tid - 1] : 0;
        int gb = atomicAdd(&cursor[tid], cnt[tid]);
        gpos[tid] = tid * BKT_CAP + gb - excl;
        cnt[tid] = excl;  // reuse as stage base
    }
    __syncthreads();
#pragma unroll
    for (int t = 0; t < EPT; ++t) {
        if (myb[t] >= 0) {
            int p = cnt[myb[t]] + myoff[t];
            stage[p] = make_int2(mys[t], myd[t]);
            bb[p] = (unsigned char)myb[t];
        }
    }
    __syncthreads();
    for (int j = tid; j < v; j += 256) {
        pairs[gpos[bb[j]] + j] = stage[j];  // mostly-contiguous runs per bucket
    }
}

// ---------- pass B: per-bucket local hist + scan + ordered eidx fill ----------
__global__ void csrB_kernel(const int2* __restrict__ pairs, const int* __restrict__ cursor,
                            int* __restrict__ deg, int* __restrict__ rowstart,
                            int* __restrict__ eidx, int n) {
    __shared__ int ldeg[NPB];
    __shared__ int lcur[NPB];
    __shared__ int scanbuf[512];
    __shared__ int s_ebase;
    int b = blockIdx.x;
    int tid = threadIdx.x;
    int node0 = b << BKT_SHIFT;
    if (node0 >= n) return;
    int nl = n - node0;
    if (nl > NPB) nl = NPB;
    int cnt_b = cursor[b];
    for (int i = tid; i < NPB; i += 512) ldeg[i] = 0;
    if (tid == 0) {
        int s = 0;
        for (int q = 0; q < b; ++q) s += cursor[q];
        s_ebase = s;
    }
    __syncthreads();
    const int2* mp = pairs + (size_t)b * BKT_CAP;
    for (int i = tid; i < cnt_b; i += 512)
        atomicAdd(&ldeg[mp[i].y - node0], 1);
    __syncthreads();
    int base = tid * 4;
    int ts = ldeg[base] + ldeg[base + 1] + ldeg[base + 2] + ldeg[base + 3];
    scanbuf[tid] = ts;
    __syncthreads();
    for (int off = 1; off < 512; off <<= 1) {
        int t = (tid >= off) ? scanbuf[tid - off] : 0;
        __syncthreads();
        scanbuf[tid] += t;
        __syncthreads();
    }
    int ex = tid ? scanbuf[tid - 1] : 0;
    int ebase = s_ebase;
#pragma unroll
    for (int j = 0; j < 4; ++j) {
        lcur[base + j] = ex;
        if (base + j < nl) {
            deg[node0 + base + j] = ldeg[base + j];
            rowstart[node0 + base + j] = ebase + ex;
        }
        ex += ldeg[base + j];
    }
    __syncthreads();
    for (int i = tid; i < cnt_b; i += 512) {
        int2 p = mp[i];
        int pos = atomicAdd(&lcur[p.y - node0], 1);
        eidx[ebase + pos] = p.x;  // lands in contiguous ~130 KB window (L2)
    }
}

// ---------- dis = rsqrt(deg) ; c = mean @ W1[64:] ----------
__global__ void finalize_kernel(const int* __restrict__ deg, float* __restrict__ dis,
                                const float* __restrict__ sums, const float* __restrict__ W1,
                                float* __restrict__ c, int n) {
    int i = blockIdx.x * blockDim.x + threadIdx.x;
    if (i < n) {
        int d = deg[i];
        dis[i] = d > 0 ? rsqrtf((float)d) : 0.f;
    }
    if (blockIdx.x == 0 && threadIdx.x < 64) {
        int j = threadIdx.x;
        float inv_n = 1.0f / (float)n;
        float acc = 0.f;
        for (int k = 0; k < 64; ++k) acc += (sums[k] * inv_n) * W1[(64 + k) * 64 + j];
        c[j] = acc;
    }
}

// ---------- h1s = dis[row] * (x @ W1[:64] + c); 4 rows x 4 cols per thread ----------
__global__ __launch_bounds__(256, 4) void gemm1_kernel(
        const float* __restrict__ x, const float* __restrict__ W1,
        const float* __restrict__ c, const float* __restrict__ dis,
        float* __restrict__ h1s, int n) {
    __shared__ float Ws[64 * 64];   // [k][j]; b128 over j: 2-way alias = free
    __shared__ float Xs[64 * 68];   // pad 68: float4-aligned stores, 2-way read alias
    int tid = threadIdx.x;
    int row0 = blockIdx.x * 64;
    {
        const float4* w4 = (const float4*)W1;
        float4* s4 = (float4*)Ws;
        for (int i = tid; i < 1024; i += 256) s4[i] = w4[i];
    }
    for (int i = tid; i < 1024; i += 256) {
        int r = i >> 4, c4 = (i & 15) * 4;
        int gr = row0 + r;
        float4 xv = make_float4(0.f, 0.f, 0.f, 0.f);
        if (gr < n) xv = *(const float4*)&x[(size_t)gr * 64 + c4];
        *(float4*)&Xs[r * 68 + c4] = xv;
    }
    __syncthreads();
    int c16 = tid & 15;
    int rb = (tid >> 4) * 4;
    float4 cj = ((const float4*)c)[c16];
    float4 a0 = cj, a1 = cj, a2 = cj, a3 = cj;
#pragma unroll 4
    for (int k = 0; k < 64; ++k) {
        float4 w = *(const float4*)&Ws[k * 64 + c16 * 4];
        float x0 = Xs[(rb + 0) * 68 + k];
        float x1 = Xs[(rb + 1) * 68 + k];
        float x2 = Xs[(rb + 2) * 68 + k];
        float x3 = Xs[(rb + 3) * 68 + k];
        a0.x += x0 * w.x; a0.y += x0 * w.y; a0.z += x0 * w.z; a0.w += x0 * w.w;
        a1.x += x1 * w.x; a1.y += x1 * w.y; a1.z += x1 * w.z; a1.w += x1 * w.w;
        a2.x += x2 * w.x; a2.y += x2 * w.y; a2.z += x2 * w.z; a2.w += x2 * w.w;
        a3.x += x3 * w.x; a3.y += x3 * w.y; a3.z += x3 * w.z; a3.w += x3 * w.w;
    }
    float4 accs[4] = {a0, a1, a2, a3};
#pragma unroll
    for (int r = 0; r < 4; ++r) {
        int gr = row0 + rb + r;
        if (gr < n) {
            float dv = dis[gr];
            float4 o = accs[r];
            o.x *= dv; o.y *= dv; o.z *= dv; o.w *= dv;
            *(float4*)&h1s[(size_t)gr * 64 + c16 * 4] = o;
        }
    }
}

// ---------- layer-1 gather + bias + relu + @W2 + src-prescale, one wave per node ----------
__global__ void gather1_kernel(const int* __restrict__ rowstart, const int* __restrict__ deg,
                               const int* __restrict__ eidx, const float* __restrict__ dis,
                               const float* __restrict__ h1s, const float* __restrict__ b1,
                               const float* __restrict__ W2, float* __restrict__ h2s, int n) {
    int lane = threadIdx.x & 63;
    int node = blockIdx.x * 4 + (threadIdx.x >> 6);
    if (node >= n) return;
    int rs = rowstart[node];
    int dn = deg[node];
    float acc = 0.f;
    int j = 0;
    for (; j + 4 <= dn; j += 4) {
        int s0 = eidx[rs + j + 0];
        int s1 = eidx[rs + j + 1];
        int s2 = eidx[rs + j + 2];
        int s3 = eidx[rs + j + 3];
        float a = h1s[(size_t)s0 * 64 + lane];
        float b = h1s[(size_t)s1 * 64 + lane];
        float cc = h1s[(size_t)s2 * 64 + lane];
        float d = h1s[(size_t)s3 * 64 + lane];
        acc += (a + b) + (cc + d);
    }
    for (; j < dn; ++j) acc += h1s[(size_t)eidx[rs + j] * 64 + lane];
    float di = dis[node];
    float t = di * acc + b1[lane];
    t = fmaxf(t, 0.f);
    float v0 = t * W2[lane * 2 + 0];
    float v1 = t * W2[lane * 2 + 1];
#pragma unroll
    for (int off = 32; off > 0; off >>= 1) {
        v0 += __shfl_down(v0, off, 64);
        v1 += __shfl_down(v1, off, 64);
    }
    if (lane == 0) {
        h2s[(size_t)node * 2 + 0] = di * v0;
        h2s[(size_t)node * 2 + 1] = di * v1;
    }
}

// ---------- layer-2 gather, one thread per node ----------
__global__ void gather2_kernel(const int* __restrict__ rowstart, const int* __restrict__ deg,
                               const int* __restrict__ eidx, const float* __restrict__ dis,
                               const float* __restrict__ h2s, const float* __restrict__ b2,
                               float* __restrict__ out, int n) {
    int i = blockIdx.x * blockDim.x + threadIdx.x;
    if (i >= n) return;
    int rs = rowstart[i];
    int dn = deg[i];
    float a0 = 0.f, a1 = 0.f, b0 = 0.f, b1v = 0.f;
    int j = 0;
    for (; j + 2 <= dn; j += 2) {
        int s0 = eidx[rs + j];
        int s1 = eidx[rs + j + 1];
        a0 += h2s[(size_t)s0 * 2 + 0];
        a1 += h2s[(size_t)s0 * 2 + 1];
        b0 += h2s[(size_t)s1 * 2 + 0];
        b1v += h2s[(size_t)s1 * 2 + 1];
    }
    if (j < dn) {
        int s0 = eidx[rs + j];
        a0 += h2s[(size_t)s0 * 2 + 0];
        a1 += h2s[(size_t)s0 * 2 + 1];
    }
    float di = dis[i];
    out[(size_t)i * 2 + 0] = di * (a0 + b0) + b2[0];
    out[(size_t)i * 2 + 1] = di * (a1 + b1v) + b2[1];
}

extern "C" void kernel_launch(void* const* d_in, const int* in_sizes, int n_in,
                              void* d_out, int out_size, void* d_ws, size_t ws_size,
                              hipStream_t stream) {
    const float* x  = (const float*)d_in[0];
    const int*   ei = (const int*)d_in[1];
    const float* W1 = (const float*)d_in[2];
    const float* b1 = (const float*)d_in[3];
    const float* W2 = (const float*)d_in[4];
    const float* b2 = (const float*)d_in[5];
    float* out = (float*)d_out;

    const int n = in_sizes[0] / 64;   // 100000
    const int e = in_sizes[1] / 2;    // 1600000
    const int* srcI = ei;
    const int* dstI = ei + e;

    // workspace layout (256-B aligned segments)
    char* p = (char*)d_ws;
    int* deg      = (int*)p;    p += ((size_t)n * 4 + 255) & ~255ull;
    int* rowstart = (int*)p;    p += ((size_t)n * 4 + 255) & ~255ull;
    float* dis    = (float*)p;  p += ((size_t)n * 4 + 255) & ~255ull;
    float* sums   = (float*)p;  p += 256;
    float* cvec   = (float*)p;  p += 256;
    int* cursor   = (int*)p;    p += 256;
    int* eidx     = (int*)p;    p += ((size_t)e * 4 + 255) & ~255ull;
    // union: pairs (18.9 MB) dead before gemm1 writes h1s (25.6 MB)
    int2* pairs   = (int2*)p;
    float* h1s    = (float*)p;
    {
        size_t pairs_sz = (size_t)BKT * BKT_CAP * 8;
        size_t h1s_sz   = (size_t)n * 64 * 4;
        size_t u = pairs_sz > h1s_sz ? pairs_sz : h1s_sz;
        p += (u + 255) & ~255ull;
    }
    float* h2s    = (float*)p;

    hipMemsetAsync(cursor, 0, 256, stream);
    hipMemsetAsync(sums, 0, 256, stream);

    const int nchunks = (e + CHUNK - 1) / CHUNK;           // 782
    const int nbkt    = (n + NPB - 1) / NPB;               // 49

    colsum_kernel<<<1024, 256, 0, stream>>>(x, sums, (long long)n * 64);
    bucketA_kernel<<<nchunks, 256, 0, stream>>>(srcI, dstI, e, pairs, cursor);
    csrB_kernel<<<nbkt, 512, 0, stream>>>(pairs, cursor, deg, rowstart, eidx, n);
    finalize_kernel<<<(n + 255) / 256, 256, 0, stream>>>(deg, dis, sums, W1, cvec, n);
    gemm1_kernel<<<(n + 63) / 64, 256, 0, stream>>>(x, W1, cvec, dis, h1s, n);
    gather1_kernel<<<(n + 3) / 4, 256, 0, stream>>>(rowstart, deg, eidx, dis, h1s, b1, W2, h2s, n);
    gather2_kernel<<<(n + 255) / 256, 256, 0, stream>>>(rowstart, deg, eidx, dis, h2s, b2, out, n);
}

// Round 4
// 263.250 us; speedup vs baseline: 2.9080x; 1.0910x over previous
//
#include <hip/hip_runtime.h>

// GCN 2-layer, CSR-by-dst gather formulation; h1s stored in bf16 (halves the
// dominant random-gather traffic; one extra RNE rounding, absmax ~5e-4 < 1.7e-3).
// out = A_hat( relu( A_hat( [x|mean]@W1 ) + b1 ) @ W2 ) + b2
// Identity: [x|mean]@W1 = x@W1[:64] + c, c = mean@W1[64:].
// Pre-scaling: h1s[s] = dis[s]*(xW1+c)[s];  h2s[s] = dis[s]*(relu(.)@W2)[s].

#define BKT        64      // dst-range buckets
#define BKT_SHIFT  11      // 2048 nodes per bucket
#define NPB        2048
#define BKT_CAP    36864   // >> max bucket count (~32.7K)
#define CHUNK      2048    // edges per bucketA block
#define EPT        8       // edges per thread in bucketA

__device__ __forceinline__ unsigned short f2bf(float v) {
    unsigned u = __float_as_uint(v);
    u += 0x7FFFu + ((u >> 16) & 1u);   // round-to-nearest-even
    return (unsigned short)(u >> 16);
}
__device__ __forceinline__ float bf2f(unsigned short h) {
    return __uint_as_float((unsigned)h << 16);
}

// ---------- column sums of x (for mean) ----------
__global__ void colsum_kernel(const float* __restrict__ x, float* __restrict__ sums,
                              long long total) {
    int tid = threadIdx.x;
    long long g = (long long)blockIdx.x * blockDim.x + tid;
    long long stride = (long long)gridDim.x * blockDim.x;  // multiple of 64 -> column fixed
    float acc = 0.f;
    for (; g < total; g += stride) acc += x[g];
    __shared__ float s[256];
    s[tid] = acc;
    __syncthreads();
    if (tid < 64) {
        float v = s[tid] + s[tid + 64] + s[tid + 128] + s[tid + 192];
        atomicAdd(&sums[tid], v);
    }
}

// ---------- pass A: LDS multi-split of edges into dst-range buckets ----------
__global__ void bucketA_kernel(const int* __restrict__ src, const int* __restrict__ dst,
                               int e, int2* __restrict__ pairs, int* __restrict__ cursor) {
    __shared__ int cnt[BKT], sb[BKT], gpos[BKT];
    __shared__ int2 stage[CHUNK];
    __shared__ unsigned char bb[CHUNK];
    int tid = threadIdx.x;
    int chunkStart = blockIdx.x * CHUNK;
    int v = e - chunkStart;
    if (v > CHUNK) v = CHUNK;
    if (tid < BKT) cnt[tid] = 0;
    __syncthreads();
    int myb[EPT], myoff[EPT], mys[EPT], myd[EPT];
#pragma unroll
    for (int t = 0; t < EPT; ++t) {
        int i = chunkStart + t * 256 + tid;
        myb[t] = -1;
        if (i < e) {
            mys[t] = src[i];
            myd[t] = dst[i];
            myb[t] = myd[t] >> BKT_SHIFT;
            myoff[t] = atomicAdd(&cnt[myb[t]], 1);
        }
    }
    __syncthreads();
    if (tid < BKT) sb[tid] = cnt[tid];
    __syncthreads();
    for (int off = 1; off < BKT; off <<= 1) {
        int t = (tid < BKT && tid >= off) ? sb[tid - off] : 0;
        __syncthreads();
        if (tid < BKT) sb[tid] += t;
        __syncthreads();
    }
    if (tid < BKT) {
        int excl = tid ? sb[tid - 1] : 0;
        int gb = atomicAdd(&cursor[tid], cnt[tid]);
        gpos[tid] = tid * BKT_CAP + gb - excl;
        cnt[tid] = excl;  // reuse as stage base
    }
    __syncthreads();
#pragma unroll
    for (int t = 0; t < EPT; ++t) {
        if (myb[t] >= 0) {
            int p = cnt[myb[t]] + myoff[t];
            stage[p] = make_int2(mys[t], myd[t]);
            bb[p] = (unsigned char)myb[t];
        }
    }
    __syncthreads();
    for (int j = tid; j < v; j += 256) {
        pairs[gpos[bb[j]] + j] = stage[j];  // mostly-contiguous runs per bucket
    }
}

// ---------- pass B: per-bucket hist + scan + ordered eidx fill; emits dis + rowstart ----------
__global__ void csrB_kernel(const int2* __restrict__ pairs, const int* __restrict__ cursor,
                            float* __restrict__ dis, int* __restrict__ rowstart,
                            int* __restrict__ eidx, int n) {
    __shared__ int ldeg[NPB];
    __shared__ int lcur[NPB];
    __shared__ int scanbuf[512];
    __shared__ int s_ebase;
    int b = blockIdx.x;
    int tid = threadIdx.x;
    int node0 = b << BKT_SHIFT;
    if (node0 >= n) return;
    int nl = n - node0;
    if (nl > NPB) nl = NPB;
    int cnt_b = cursor[b];
    for (int i = tid; i < NPB; i += 512) ldeg[i] = 0;
    if (tid == 0) {
        int s = 0;
        for (int q = 0; q < b; ++q) s += cursor[q];
        s_ebase = s;
    }
    __syncthreads();
    const int2* mp = pairs + (size_t)b * BKT_CAP;
    for (int i = tid; i < cnt_b; i += 512)
        atomicAdd(&ldeg[mp[i].y - node0], 1);
    __syncthreads();
    int base = tid * 4;
    int ts = ldeg[base] + ldeg[base + 1] + ldeg[base + 2] + ldeg[base + 3];
    scanbuf[tid] = ts;
    __syncthreads();
    for (int off = 1; off < 512; off <<= 1) {
        int t = (tid >= off) ? scanbuf[tid - off] : 0;
        __syncthreads();
        scanbuf[tid] += t;
        __syncthreads();
    }
    int ex = tid ? scanbuf[tid - 1] : 0;
    int ebase = s_ebase;
#pragma unroll
    for (int j = 0; j < 4; ++j) {
        lcur[base + j] = ex;
        if (base + j < nl) {
            int dv = ldeg[base + j];
            rowstart[node0 + base + j] = ebase + ex;
            dis[node0 + base + j] = dv > 0 ? rsqrtf((float)dv) : 0.f;
        }
        ex += ldeg[base + j];
    }
    if (tid == 0 && node0 + NPB >= n)          // last bucket: close the CSR
        rowstart[n] = ebase + cnt_b;
    __syncthreads();
    for (int i = tid; i < cnt_b; i += 512) {
        int2 p = mp[i];
        int pos = atomicAdd(&lcur[p.y - node0], 1);
        eidx[ebase + pos] = p.x;  // contiguous ~130 KB window (L2-resident)
    }
}

// ---------- c = mean @ W1[64:] ----------
__global__ void cvec_kernel(const float* __restrict__ sums, const float* __restrict__ W1,
                            float* __restrict__ c, int n) {
    int j = threadIdx.x;  // 64 threads
    float inv_n = 1.0f / (float)n;
    float acc = 0.f;
    for (int k = 0; k < 64; ++k) acc += (sums[k] * inv_n) * W1[(64 + k) * 64 + j];
    c[j] = acc;
}

// ---------- h1s(bf16) = dis[row] * (x @ W1[:64] + c); 4 rows x 4 cols/thread ----------
__global__ __launch_bounds__(256, 4) void gemm1_kernel(
        const float* __restrict__ x, const float* __restrict__ W1,
        const float* __restrict__ c, const float* __restrict__ dis,
        unsigned short* __restrict__ h1s, int n) {
    __shared__ float Ws[64 * 64];   // [k][j]
    __shared__ float Xs[64 * 68];   // pad 68
    int tid = threadIdx.x;
    int row0 = blockIdx.x * 64;
    {
        const float4* w4 = (const float4*)W1;
        float4* s4 = (float4*)Ws;
        for (int i = tid; i < 1024; i += 256) s4[i] = w4[i];
    }
    for (int i = tid; i < 1024; i += 256) {
        int r = i >> 4, c4 = (i & 15) * 4;
        int gr = row0 + r;
        float4 xv = make_float4(0.f, 0.f, 0.f, 0.f);
        if (gr < n) xv = *(const float4*)&x[(size_t)gr * 64 + c4];
        *(float4*)&Xs[r * 68 + c4] = xv;
    }
    __syncthreads();
    int c16 = tid & 15;
    int rb = (tid >> 4) * 4;
    float4 cj = ((const float4*)c)[c16];
    float4 a0 = cj, a1 = cj, a2 = cj, a3 = cj;
#pragma unroll 4
    for (int k = 0; k < 64; ++k) {
        float4 w = *(const float4*)&Ws[k * 64 + c16 * 4];
        float x0 = Xs[(rb + 0) * 68 + k];
        float x1 = Xs[(rb + 1) * 68 + k];
        float x2 = Xs[(rb + 2) * 68 + k];
        float x3 = Xs[(rb + 3) * 68 + k];
        a0.x += x0 * w.x; a0.y += x0 * w.y; a0.z += x0 * w.z; a0.w += x0 * w.w;
        a1.x += x1 * w.x; a1.y += x1 * w.y; a1.z += x1 * w.z; a1.w += x1 * w.w;
        a2.x += x2 * w.x; a2.y += x2 * w.y; a2.z += x2 * w.z; a2.w += x2 * w.w;
        a3.x += x3 * w.x; a3.y += x3 * w.y; a3.z += x3 * w.z; a3.w += x3 * w.w;
    }
    float4 accs[4] = {a0, a1, a2, a3};
#pragma unroll
    for (int r = 0; r < 4; ++r) {
        int gr = row0 + rb + r;
        if (gr < n) {
            float dv = dis[gr];
            float4 o = accs[r];
            ushort4 hs;
            hs.x = f2bf(o.x * dv);
            hs.y = f2bf(o.y * dv);
            hs.z = f2bf(o.z * dv);
            hs.w = f2bf(o.w * dv);
            *(ushort4*)&h1s[(size_t)gr * 64 + c16 * 4] = hs;
        }
    }
}

// ---------- layer-1 gather + bias + relu + @W2 + src-prescale, one wave/node ----------
__global__ void gather1_kernel(const int* __restrict__ rowstart,
                               const int* __restrict__ eidx, const float* __restrict__ dis,
                               const unsigned short* __restrict__ h1s,
                               const float* __restrict__ b1, const float* __restrict__ W2,
                               float* __restrict__ h2s, int n) {
    int lane = threadIdx.x & 63;
    int node = blockIdx.x * 4 + (threadIdx.x >> 6);
    if (node >= n) return;
    int rs = rowstart[node];
    int re = rowstart[node + 1];
    int dn = re - rs;
    int m = dn < 64 ? dn : 64;
    int eHeld = (lane < m) ? eidx[rs + lane] : 0;  // one coalesced load for <=64 edges
    float acc = 0.f;
    int j = 0;
    for (; j + 8 <= m; j += 8) {
        int s0 = __shfl(eHeld, j + 0, 64);
        int s1 = __shfl(eHeld, j + 1, 64);
        int s2 = __shfl(eHeld, j + 2, 64);
        int s3 = __shfl(eHeld, j + 3, 64);
        int s4 = __shfl(eHeld, j + 4, 64);
        int s5 = __shfl(eHeld, j + 5, 64);
        int s6 = __shfl(eHeld, j + 6, 64);
        int s7 = __shfl(eHeld, j + 7, 64);
        float a = bf2f(h1s[(size_t)s0 * 64 + lane]);
        float b = bf2f(h1s[(size_t)s1 * 64 + lane]);
        float cc = bf2f(h1s[(size_t)s2 * 64 + lane]);
        float d = bf2f(h1s[(size_t)s3 * 64 + lane]);
        float e4 = bf2f(h1s[(size_t)s4 * 64 + lane]);
        float f = bf2f(h1s[(size_t)s5 * 64 + lane]);
        float g = bf2f(h1s[(size_t)s6 * 64 + lane]);
        float h = bf2f(h1s[(size_t)s7 * 64 + lane]);
        acc += ((a + b) + (cc + d)) + ((e4 + f) + (g + h));
    }
    for (; j + 4 <= m; j += 4) {
        int s0 = __shfl(eHeld, j + 0, 64);
        int s1 = __shfl(eHeld, j + 1, 64);
        int s2 = __shfl(eHeld, j + 2, 64);
        int s3 = __shfl(eHeld, j + 3, 64);
        float a = bf2f(h1s[(size_t)s0 * 64 + lane]);
        float b = bf2f(h1s[(size_t)s1 * 64 + lane]);
        float cc = bf2f(h1s[(size_t)s2 * 64 + lane]);
        float d = bf2f(h1s[(size_t)s3 * 64 + lane]);
        acc += (a + b) + (cc + d);
    }
    for (; j < m; ++j) {
        int s0 = __shfl(eHeld, j, 64);
        acc += bf2f(h1s[(size_t)s0 * 64 + lane]);
    }
    for (; j < dn; ++j) {  // rare: deg > 64
        int s0 = eidx[rs + j];
        acc += bf2f(h1s[(size_t)s0 * 64 + lane]);
    }
    float di = dis[node];
    float t = di * acc + b1[lane];
    t = fmaxf(t, 0.f);
    float v0 = t * W2[lane * 2 + 0];
    float v1 = t * W2[lane * 2 + 1];
#pragma unroll
    for (int off = 32; off > 0; off >>= 1) {
        v0 += __shfl_down(v0, off, 64);
        v1 += __shfl_down(v1, off, 64);
    }
    if (lane == 0) {
        h2s[(size_t)node * 2 + 0] = di * v0;
        h2s[(size_t)node * 2 + 1] = di * v1;
    }
}

// ---------- layer-2 gather, one thread per node ----------
__global__ void gather2_kernel(const int* __restrict__ rowstart,
                               const int* __restrict__ eidx, const float* __restrict__ dis,
                               const float* __restrict__ h2s, const float* __restrict__ b2,
                               float* __restrict__ out, int n) {
    int i = blockIdx.x * blockDim.x + threadIdx.x;
    if (i >= n) return;
    int rs = rowstart[i];
    int dn = rowstart[i + 1] - rs;
    float a0 = 0.f, a1 = 0.f, b0 = 0.f, b1v = 0.f;
    int j = 0;
    for (; j + 2 <= dn; j += 2) {
        int s0 = eidx[rs + j];
        int s1 = eidx[rs + j + 1];
        a0 += h2s[(size_t)s0 * 2 + 0];
        a1 += h2s[(size_t)s0 * 2 + 1];
        b0 += h2s[(size_t)s1 * 2 + 0];
        b1v += h2s[(size_t)s1 * 2 + 1];
    }
    if (j < dn) {
        int s0 = eidx[rs + j];
        a0 += h2s[(size_t)s0 * 2 + 0];
        a1 += h2s[(size_t)s0 * 2 + 1];
    }
    float di = dis[i];
    out[(size_t)i * 2 + 0] = di * (a0 + b0) + b2[0];
    out[(size_t)i * 2 + 1] = di * (a1 + b1v) + b2[1];
}

extern "C" void kernel_launch(void* const* d_in, const int* in_sizes, int n_in,
                              void* d_out, int out_size, void* d_ws, size_t ws_size,
                              hipStream_t stream) {
    const float* x  = (const float*)d_in[0];
    const int*   ei = (const int*)d_in[1];
    const float* W1 = (const float*)d_in[2];
    const float* b1 = (const float*)d_in[3];
    const float* W2 = (const float*)d_in[4];
    const float* b2 = (const float*)d_in[5];
    float* out = (float*)d_out;

    const int n = in_sizes[0] / 64;   // 100000
    const int e = in_sizes[1] / 2;    // 1600000
    const int* srcI = ei;
    const int* dstI = ei + e;

    // workspace layout (256-B aligned segments)
    char* p = (char*)d_ws;
    int* rowstart = (int*)p;    p += ((size_t)(n + 1) * 4 + 255) & ~255ull;
    float* dis    = (float*)p;  p += ((size_t)n * 4 + 255) & ~255ull;
    float* sums   = (float*)p;  p += 256;
    float* cvec   = (float*)p;  p += 256;
    int* cursor   = (int*)p;    p += 256;
    int* eidx     = (int*)p;    p += ((size_t)e * 4 + 255) & ~255ull;
    // union: pairs (18.9 MB) dead before gemm1 writes h1s (bf16, 12.8 MB)
    int2* pairs          = (int2*)p;
    unsigned short* h1s  = (unsigned short*)p;
    {
        size_t pairs_sz = (size_t)BKT * BKT_CAP * 8;
        size_t h1s_sz   = (size_t)n * 64 * 2;
        size_t u = pairs_sz > h1s_sz ? pairs_sz : h1s_sz;
        p += (u + 255) & ~255ull;
    }
    float* h2s    = (float*)p;

    hipMemsetAsync(cursor, 0, 256, stream);
    hipMemsetAsync(sums, 0, 256, stream);

    const int nchunks = (e + CHUNK - 1) / CHUNK;           // 782
    const int nbkt    = (n + NPB - 1) / NPB;               // 49

    colsum_kernel<<<1024, 256, 0, stream>>>(x, sums, (long long)n * 64);
    bucketA_kernel<<<nchunks, 256, 0, stream>>>(srcI, dstI, e, pairs, cursor);
    csrB_kernel<<<nbkt, 512, 0, stream>>>(pairs, cursor, dis, rowstart, eidx, n);
    cvec_kernel<<<1, 64, 0, stream>>>(sums, W1, cvec, n);
    gemm1_kernel<<<(n + 63) / 64, 256, 0, stream>>>(x, W1, cvec, dis, h1s, n);
    gather1_kernel<<<(n + 3) / 4, 256, 0, stream>>>(rowstart, eidx, dis, h1s, b1, W2, h2s, n);
    gather2_kernel<<<(n + 255) / 256, 256, 0, stream>>>(rowstart, eidx, dis, h2s, b2, out, n);
}

// Round 5
// 239.192 us; speedup vs baseline: 3.2005x; 1.1006x over previous
//
#include <hip/hip_runtime.h>

// GCN 2-layer, CSR-by-dst gather formulation; h1s in bf16.
// gather1: 16 lanes/edge (ushort4 per lane) -> 4 edges per load instruction.
// CSR build: 128-bucket two-pass LDS sort (98 csrB blocks).
// out = A_hat( relu( A_hat( [x|mean]@W1 ) + b1 ) @ W2 ) + b2
// Identity: [x|mean]@W1 = x@W1[:64] + c, c = mean@W1[64:].
// Pre-scaling: h1s[s] = dis[s]*(xW1+c)[s];  h2s[s] = dis[s]*(relu(.)@W2)[s].

#define BKT        128     // dst-range buckets
#define BKT_SHIFT  10      // 1024 nodes per bucket
#define NPB        1024
#define BKT_CAP    18432   // mean 16384 + 16 sigma
#define CHUNK      2048    // edges per bucketA block
#define EPT        8       // edges per thread in bucketA

__device__ __forceinline__ unsigned short f2bf(float v) {
    unsigned u = __float_as_uint(v);
    u += 0x7FFFu + ((u >> 16) & 1u);   // round-to-nearest-even
    return (unsigned short)(u >> 16);
}
__device__ __forceinline__ float bf2f(unsigned short h) {
    return __uint_as_float((unsigned)h << 16);
}

// ---------- column sums of x (for mean) ----------
__global__ void colsum_kernel(const float* __restrict__ x, float* __restrict__ sums,
                              long long total) {
    int tid = threadIdx.x;
    long long g = (long long)blockIdx.x * blockDim.x + tid;
    long long stride = (long long)gridDim.x * blockDim.x;  // multiple of 64 -> column fixed
    float acc = 0.f;
    for (; g < total; g += stride) acc += x[g];
    __shared__ float s[256];
    s[tid] = acc;
    __syncthreads();
    if (tid < 64) {
        float v = s[tid] + s[tid + 64] + s[tid + 128] + s[tid + 192];
        atomicAdd(&sums[tid], v);
    }
}

// ---------- pass A: LDS multi-split of edges into dst-range buckets ----------
__global__ void bucketA_kernel(const int* __restrict__ src, const int* __restrict__ dst,
                               int e, int2* __restrict__ pairs, int* __restrict__ cursor) {
    __shared__ int cnt[BKT], sb[BKT], gpos[BKT];
    __shared__ int2 stage[CHUNK];
    __shared__ unsigned char bb[CHUNK];
    int tid = threadIdx.x;
    int chunkStart = blockIdx.x * CHUNK;
    int v = e - chunkStart;
    if (v > CHUNK) v = CHUNK;
    if (tid < BKT) cnt[tid] = 0;
    __syncthreads();
    int myb[EPT], myoff[EPT], mys[EPT], myd[EPT];
#pragma unroll
    for (int t = 0; t < EPT; ++t) {
        int i = chunkStart + t * 256 + tid;
        myb[t] = -1;
        if (i < e) {
            mys[t] = src[i];
            myd[t] = dst[i];
            myb[t] = myd[t] >> BKT_SHIFT;
            myoff[t] = atomicAdd(&cnt[myb[t]], 1);
        }
    }
    __syncthreads();
    if (tid < BKT) sb[tid] = cnt[tid];
    __syncthreads();
    for (int off = 1; off < BKT; off <<= 1) {
        int t = (tid < BKT && tid >= off) ? sb[tid - off] : 0;
        __syncthreads();
        if (tid < BKT) sb[tid] += t;
        __syncthreads();
    }
    if (tid < BKT) {
        int excl = tid ? sb[tid - 1] : 0;
        int gb = atomicAdd(&cursor[tid], cnt[tid]);
        gpos[tid] = tid * BKT_CAP + gb - excl;
        cnt[tid] = excl;  // reuse as stage base
    }
    __syncthreads();
#pragma unroll
    for (int t = 0; t < EPT; ++t) {
        if (myb[t] >= 0) {
            int p = cnt[myb[t]] + myoff[t];
            stage[p] = make_int2(mys[t], myd[t]);
            bb[p] = (unsigned char)myb[t];
        }
    }
    __syncthreads();
    for (int j = tid; j < v; j += 256) {
        pairs[gpos[bb[j]] + j] = stage[j];  // ~128 B contiguous runs per bucket
    }
}

// ---------- pass B: per-bucket hist + scan + ordered eidx fill; emits dis + rowstart ----------
__global__ void csrB_kernel(const int2* __restrict__ pairs, const int* __restrict__ cursor,
                            float* __restrict__ dis, int* __restrict__ rowstart,
                            int* __restrict__ eidx, int n) {
    __shared__ int ldeg[NPB];
    __shared__ int lcur[NPB];
    __shared__ int scanbuf[512];
    __shared__ int s_ebase;
    int b = blockIdx.x;
    int tid = threadIdx.x;
    int node0 = b << BKT_SHIFT;
    if (node0 >= n) return;
    int nl = n - node0;
    if (nl > NPB) nl = NPB;
    int cnt_b = cursor[b];
    for (int i = tid; i < NPB; i += 512) ldeg[i] = 0;
    if (tid == 0) {
        int s = 0;
        for (int q = 0; q < b; ++q) s += cursor[q];
        s_ebase = s;
    }
    __syncthreads();
    const int2* mp = pairs + (size_t)b * BKT_CAP;
    for (int i = tid; i < cnt_b; i += 512)
        atomicAdd(&ldeg[mp[i].y - node0], 1);
    __syncthreads();
    int base = tid * 2;
    int ts = ldeg[base] + ldeg[base + 1];
    scanbuf[tid] = ts;
    __syncthreads();
    for (int off = 1; off < 512; off <<= 1) {
        int t = (tid >= off) ? scanbuf[tid - off] : 0;
        __syncthreads();
        scanbuf[tid] += t;
        __syncthreads();
    }
    int ex = tid ? scanbuf[tid - 1] : 0;
    int ebase = s_ebase;
#pragma unroll
    for (int j = 0; j < 2; ++j) {
        lcur[base + j] = ex;
        if (base + j < nl) {
            int dv = ldeg[base + j];
            rowstart[node0 + base + j] = ebase + ex;
            dis[node0 + base + j] = dv > 0 ? rsqrtf((float)dv) : 0.f;
        }
        ex += ldeg[base + j];
    }
    if (tid == 0 && node0 + NPB >= n)          // last bucket: close the CSR
        rowstart[n] = ebase + cnt_b;
    __syncthreads();
    for (int i = tid; i < cnt_b; i += 512) {
        int2 p = mp[i];
        int pos = atomicAdd(&lcur[p.y - node0], 1);
        eidx[ebase + pos] = p.x;  // contiguous ~65 KB window (L2-resident)
    }
}

// ---------- c = mean @ W1[64:] ----------
__global__ void cvec_kernel(const float* __restrict__ sums, const float* __restrict__ W1,
                            float* __restrict__ c, int n) {
    int j = threadIdx.x;  // 64 threads
    float inv_n = 1.0f / (float)n;
    float acc = 0.f;
    for (int k = 0; k < 64; ++k) acc += (sums[k] * inv_n) * W1[(64 + k) * 64 + j];
    c[j] = acc;
}

// ---------- h1s(bf16) = dis[row] * (x @ W1[:64] + c); 4 rows x 4 cols/thread ----------
__global__ __launch_bounds__(256, 4) void gemm1_kernel(
        const float* __restrict__ x, const float* __restrict__ W1,
        const float* __restrict__ c, const float* __restrict__ dis,
        unsigned short* __restrict__ h1s, int n) {
    __shared__ float Ws[64 * 64];   // [k][j]
    __shared__ float Xs[64 * 68];   // pad 68
    int tid = threadIdx.x;
    int row0 = blockIdx.x * 64;
    {
        const float4* w4 = (const float4*)W1;
        float4* s4 = (float4*)Ws;
        for (int i = tid; i < 1024; i += 256) s4[i] = w4[i];
    }
    for (int i = tid; i < 1024; i += 256) {
        int r = i >> 4, c4 = (i & 15) * 4;
        int gr = row0 + r;
        float4 xv = make_float4(0.f, 0.f, 0.f, 0.f);
        if (gr < n) xv = *(const float4*)&x[(size_t)gr * 64 + c4];
        *(float4*)&Xs[r * 68 + c4] = xv;
    }
    __syncthreads();
    int c16 = tid & 15;
    int rb = (tid >> 4) * 4;
    float4 cj = ((const float4*)c)[c16];
    float4 a0 = cj, a1 = cj, a2 = cj, a3 = cj;
#pragma unroll 4
    for (int k = 0; k < 64; ++k) {
        float4 w = *(const float4*)&Ws[k * 64 + c16 * 4];
        float x0 = Xs[(rb + 0) * 68 + k];
        float x1 = Xs[(rb + 1) * 68 + k];
        float x2 = Xs[(rb + 2) * 68 + k];
        float x3 = Xs[(rb + 3) * 68 + k];
        a0.x += x0 * w.x; a0.y += x0 * w.y; a0.z += x0 * w.z; a0.w += x0 * w.w;
        a1.x += x1 * w.x; a1.y += x1 * w.y; a1.z += x1 * w.z; a1.w += x1 * w.w;
        a2.x += x2 * w.x; a2.y += x2 * w.y; a2.z += x2 * w.z; a2.w += x2 * w.w;
        a3.x += x3 * w.x; a3.y += x3 * w.y; a3.z += x3 * w.z; a3.w += x3 * w.w;
    }
    float4 accs[4] = {a0, a1, a2, a3};
#pragma unroll
    for (int r = 0; r < 4; ++r) {
        int gr = row0 + rb + r;
        if (gr < n) {
            float dv = dis[gr];
            float4 o = accs[r];
            ushort4 hs;
            hs.x = f2bf(o.x * dv);
            hs.y = f2bf(o.y * dv);
            hs.z = f2bf(o.z * dv);
            hs.w = f2bf(o.w * dv);
            *(ushort4*)&h1s[(size_t)gr * 64 + c16 * 4] = hs;
        }
    }
}

// ---------- layer-1 gather: 16 lanes per edge, ushort4 per lane; one wave/node ----------
__global__ void gather1_kernel(const int* __restrict__ rowstart,
                               const int* __restrict__ eidx, const float* __restrict__ dis,
                               const unsigned short* __restrict__ h1s,
                               const float* __restrict__ b1, const float* __restrict__ W2,
                               float* __restrict__ h2s, int n) {
    int lane = threadIdx.x & 63;
    int node = blockIdx.x * 4 + (threadIdx.x >> 6);
    if (node >= n) return;
    int rs = rowstart[node];
    int re = rowstart[node + 1];
    int dn = re - rs;
    int m = dn < 64 ? dn : 64;
    int eHeld = (lane < m) ? eidx[rs + lane] : 0;  // one coalesced load for <=64 edges
    int g  = lane >> 4;        // edge subgroup 0..3
    int fb = (lane & 15) * 4;  // feature base
    float4 acc = make_float4(0.f, 0.f, 0.f, 0.f);
    int j = 0;
    for (; j + 8 <= m; j += 8) {           // 8 edges per iter, 2 loads in flight
        int sa = __shfl(eHeld, j + g, 64);
        int sb = __shfl(eHeld, j + 4 + g, 64);
        ushort4 ha = *(const ushort4*)&h1s[((size_t)sa << 6) + fb];
        ushort4 hb = *(const ushort4*)&h1s[((size_t)sb << 6) + fb];
        acc.x += bf2f(ha.x) + bf2f(hb.x);
        acc.y += bf2f(ha.y) + bf2f(hb.y);
        acc.z += bf2f(ha.z) + bf2f(hb.z);
        acc.w += bf2f(ha.w) + bf2f(hb.w);
    }
    for (; j < m; j += 4) {                // ragged tail, 0..2 iters
        int jj = j + g;
        int s = __shfl(eHeld, jj < m ? jj : 0, 64);
        if (jj < m) {
            ushort4 h = *(const ushort4*)&h1s[((size_t)s << 6) + fb];
            acc.x += bf2f(h.x);
            acc.y += bf2f(h.y);
            acc.z += bf2f(h.z);
            acc.w += bf2f(h.w);
        }
    }
    for (int t = 64; t < dn; ++t) {        // deg > 64: astronomically rare here
        if (g == 0) {
            int s = eidx[rs + t];
            ushort4 h = *(const ushort4*)&h1s[((size_t)s << 6) + fb];
            acc.x += bf2f(h.x);
            acc.y += bf2f(h.y);
            acc.z += bf2f(h.z);
            acc.w += bf2f(h.w);
        }
    }
    // reduce across the 4 edge subgroups
    acc.x += __shfl_xor(acc.x, 16, 64); acc.x += __shfl_xor(acc.x, 32, 64);
    acc.y += __shfl_xor(acc.y, 16, 64); acc.y += __shfl_xor(acc.y, 32, 64);
    acc.z += __shfl_xor(acc.z, 16, 64); acc.z += __shfl_xor(acc.z, 32, 64);
    acc.w += __shfl_xor(acc.w, 16, 64); acc.w += __shfl_xor(acc.w, 32, 64);
    float di = dis[node];
    float4 bv = ((const float4*)b1)[lane & 15];
    float4 w0 = ((const float4*)W2)[(lane & 15) * 2];      // (fb,c0)(fb,c1)(fb+1,c0)(fb+1,c1)
    float4 w1 = ((const float4*)W2)[(lane & 15) * 2 + 1];  // (fb+2..fb+3)
    float t0 = fmaxf(di * acc.x + bv.x, 0.f);
    float t1 = fmaxf(di * acc.y + bv.y, 0.f);
    float t2 = fmaxf(di * acc.z + bv.z, 0.f);
    float t3 = fmaxf(di * acc.w + bv.w, 0.f);
    float v0 = t0 * w0.x + t1 * w0.z + t2 * w1.x + t3 * w1.z;
    float v1 = t0 * w0.y + t1 * w0.w + t2 * w1.y + t3 * w1.w;
#pragma unroll
    for (int off = 1; off <= 8; off <<= 1) {   // sum the 16 feature classes
        v0 += __shfl_xor(v0, off, 64);
        v1 += __shfl_xor(v1, off, 64);
    }
    if (lane == 0) {
        h2s[(size_t)node * 2 + 0] = di * v0;
        h2s[(size_t)node * 2 + 1] = di * v1;
    }
}

// ---------- layer-2 gather, one thread per node ----------
__global__ void gather2_kernel(const int* __restrict__ rowstart,
                               const int* __restrict__ eidx, const float* __restrict__ dis,
                               const float* __restrict__ h2s, const float* __restrict__ b2,
                               float* __restrict__ out, int n) {
    int i = blockIdx.x * blockDim.x + threadIdx.x;
    if (i >= n) return;
    int rs = rowstart[i];
    int dn = rowstart[i + 1] - rs;
    float a0 = 0.f, a1 = 0.f, b0 = 0.f, b1v = 0.f;
    int j = 0;
    for (; j + 2 <= dn; j += 2) {
        int s0 = eidx[rs + j];
        int s1 = eidx[rs + j + 1];
        a0 += h2s[(size_t)s0 * 2 + 0];
        a1 += h2s[(size_t)s0 * 2 + 1];
        b0 += h2s[(size_t)s1 * 2 + 0];
        b1v += h2s[(size_t)s1 * 2 + 1];
    }
    if (j < dn) {
        int s0 = eidx[rs + j];
        a0 += h2s[(size_t)s0 * 2 + 0];
        a1 += h2s[(size_t)s0 * 2 + 1];
    }
    float di = dis[i];
    out[(size_t)i * 2 + 0] = di * (a0 + b0) + b2[0];
    out[(size_t)i * 2 + 1] = di * (a1 + b1v) + b2[1];
}

extern "C" void kernel_launch(void* const* d_in, const int* in_sizes, int n_in,
                              void* d_out, int out_size, void* d_ws, size_t ws_size,
                              hipStream_t stream) {
    const float* x  = (const float*)d_in[0];
    const int*   ei = (const int*)d_in[1];
    const float* W1 = (const float*)d_in[2];
    const float* b1 = (const float*)d_in[3];
    const float* W2 = (const float*)d_in[4];
    const float* b2 = (const float*)d_in[5];
    float* out = (float*)d_out;

    const int n = in_sizes[0] / 64;   // 100000
    const int e = in_sizes[1] / 2;    // 1600000
    const int* srcI = ei;
    const int* dstI = ei + e;

    // workspace layout (256-B aligned segments)
    char* p = (char*)d_ws;
    int* rowstart = (int*)p;    p += ((size_t)(n + 1) * 4 + 255) & ~255ull;
    float* dis    = (float*)p;  p += ((size_t)n * 4 + 255) & ~255ull;
    float* sums   = (float*)p;  p += 256;
    float* cvec   = (float*)p;  p += 256;
    int* cursor   = (int*)p;    p += 512;
    int* eidx     = (int*)p;    p += ((size_t)e * 4 + 255) & ~255ull;
    // union: pairs (18.9 MB) dead before gemm1 writes h1s (bf16, 12.8 MB)
    int2* pairs          = (int2*)p;
    unsigned short* h1s  = (unsigned short*)p;
    {
        size_t pairs_sz = (size_t)BKT * BKT_CAP * 8;
        size_t h1s_sz   = (size_t)n * 64 * 2;
        size_t u = pairs_sz > h1s_sz ? pairs_sz : h1s_sz;
        p += (u + 255) & ~255ull;
    }
    float* h2s    = (float*)p;

    hipMemsetAsync(cursor, 0, 512, stream);
    hipMemsetAsync(sums, 0, 256, stream);

    const int nchunks = (e + CHUNK - 1) / CHUNK;           // 782
    const int nbkt    = (n + NPB - 1) / NPB;               // 98

    colsum_kernel<<<1024, 256, 0, stream>>>(x, sums, (long long)n * 64);
    bucketA_kernel<<<nchunks, 256, 0, stream>>>(srcI, dstI, e, pairs, cursor);
    csrB_kernel<<<nbkt, 512, 0, stream>>>(pairs, cursor, dis, rowstart, eidx, n);
    cvec_kernel<<<1, 64, 0, stream>>>(sums, W1, cvec, n);
    gemm1_kernel<<<(n + 63) / 64, 256, 0, stream>>>(x, W1, cvec, dis, h1s, n);
    gather1_kernel<<<(n + 3) / 4, 256, 0, stream>>>(rowstart, eidx, dis, h1s, b1, W2, h2s, n);
    gather2_kernel<<<(n + 255) / 256, 256, 0, stream>>>(rowstart, eidx, dis, h2s, b2, out, n);
}